// Round 15
// baseline (28.816 us; speedup 1.0000x reference)
//
#include <hip/hip_runtime.h>
#include <math.h>

// B=4096, O=8, E=64, I=4, V=3, P=perm(8,3)=336
// unary_feats  (B,8,64)   f32
// binary_feats (B,8,8,64) f32
// rule_unary   (4,3,64)   f32  = [12][64]
// rule_binary  (4,3,3,64) f32  = [36][64]  (rule = i*9 + n*3 + m)
// out          (B,4)      f32  (col0=sel0+sel1, col1=sel2+sel3, col2=col3=0)
//
// v15 = v11 algorithm, occupancy-first: 1 element per wave, 4096 one-wave
// blocks, __launch_bounds__(64,4) -> 4 waves/SIMD, and LDS squeezed to
// 10.08 KB so 16 blocks/CU => the ENTIRE grid is co-resident; all load
// bursts overlap chip-wide (TLP replaces the software pipeline).
// LDS: one smem[] array; bm = 36 rows x stride 66 ([rule][pos]);
// q (12 rows x 66) OVERLAYS bm rows 0..11 (bm dead there by write time:
// per-wave DS ops are in-order; phase-2 iter i reads bm rows 9i..9i+8 and
// writes q rows 3i..3i+2 -- row sets never collide within an iteration);
// um (12 x 12) sits after bm. Zero barriers (wave-private LDS).

typedef __attribute__((ext_vector_type(8))) __bf16 bf16x8;
typedef __attribute__((ext_vector_type(4))) float  f32x4;

#define BMS 66   // bm/q row stride (floats)
#define SSU 12   // um row stride

__device__ inline bf16x8 cvt2(const float4 v0, const float4 v1) {
    bf16x8 r;
    r[0] = (__bf16)v0.x; r[1] = (__bf16)v0.y; r[2] = (__bf16)v0.z; r[3] = (__bf16)v0.w;
    r[4] = (__bf16)v1.x; r[5] = (__bf16)v1.y; r[6] = (__bf16)v1.z; r[7] = (__bf16)v1.w;
    return r;
}

__global__ __launch_bounds__(64, 4) void rule_learner_kernel(
    const float* __restrict__ uf,    // (B,8,64)
    const float* __restrict__ bfe,   // (B,8,8,64)
    const float* __restrict__ ru,    // [12][64]
    const float* __restrict__ rb,    // [36][64]
    float* __restrict__ out)         // (B,4)
{
    const int b     = blockIdx.x;
    const int lane  = threadIdx.x;   // one wave per block
    const int row16 = lane & 15;
    const int kg    = lane >> 4;
    const int kb    = kg * 8;

    __shared__ float smem[36 * BMS + 12 * SSU];   // 10080 B
    float* bm = smem;                 // [rule 0..35][pos], stride 66
    float* qq = smem;                 // q rows 0..11 overlay bm rows 0..11
    float* um = smem + 36 * BMS;      // [i*3+n][v], stride 12

    // ---- feature loads, converted to bf16 fragments on arrival (VGPR diet) ----
    bf16x8 a0[4], a1[4], ua0, ua1;
    {
        const float* base = bfe + (size_t)b * 4096;
        #pragma unroll
        for (int t = 0; t < 4; ++t) {
            const float* rp = base + (size_t)(t * 16 + row16) * 64 + kb;
            a0[t] = cvt2(*(const float4*)rp,        *(const float4*)(rp + 4));
            a1[t] = cvt2(*(const float4*)(rp + 32), *(const float4*)(rp + 36));
        }
        const float* up = uf + (size_t)b * 512 + (row16 < 8 ? row16 : 7) * 64 + kb;
        ua0 = cvt2(*(const float4*)up,        *(const float4*)(up + 4));
        ua1 = cvt2(*(const float4*)(up + 32), *(const float4*)(up + 36));
    }

    // ---- rule B-fragments packed in-wave (L1-hot f32; clamp padding) ----
    bf16x8 rbf[6], ruf0, ruf1;
    {
        #pragma unroll
        for (int nt = 0; nt < 3; ++nt) {
            const int rule = nt * 16 + row16;
            const float* rp = rb + (rule < 36 ? rule : 35) * 64 + kb;
            rbf[nt * 2 + 0] = cvt2(*(const float4*)rp,        *(const float4*)(rp + 4));
            rbf[nt * 2 + 1] = cvt2(*(const float4*)(rp + 32), *(const float4*)(rp + 36));
        }
        const float* up = ru + (row16 < 12 ? row16 : 11) * 64 + kb;
        ruf0 = cvt2(*(const float4*)up,        *(const float4*)(up + 4));
        ruf1 = cvt2(*(const float4*)(up + 32), *(const float4*)(up + 36));
    }

    // ---- phase 1: MFMA matches into bm/um ----
    #pragma unroll
    for (int t = 0; t < 4; ++t) {
        #pragma unroll
        for (int nt = 0; nt < 3; ++nt) {
            f32x4 acc = {0.f, 0.f, 0.f, 0.f};
            acc = __builtin_amdgcn_mfma_f32_16x16x32_bf16(a0[t], rbf[nt * 2 + 0], acc, 0, 0, 0);
            acc = __builtin_amdgcn_mfma_f32_16x16x32_bf16(a1[t], rbf[nt * 2 + 1], acc, 0, 0, 0);
            // C: col = lane&15 (rule), rows = kg*4 + r (pos within tile)
            const int rule = nt * 16 + row16;
            if (rule < 36)
                *(float4*)&bm[rule * BMS + t * 16 + kg * 4] = *(float4*)&acc;
        }
    }
    {
        f32x4 acc = {0.f, 0.f, 0.f, 0.f};
        acc = __builtin_amdgcn_mfma_f32_16x16x32_bf16(ua0, ruf0, acc, 0, 0, 0);
        acc = __builtin_amdgcn_mfma_f32_16x16x32_bf16(ua1, ruf1, acc, 0, 0, 0);
        if (row16 < 12 && kg < 2)
            *(float4*)&um[row16 * SSU + kg * 4] = *(float4*)&acc;
    }

    // ---- phase 2: q-tables (lane = pair (x,y)); q rows 3i..3i+2 overlay
    //      bm rows 0..11, read-rows 9i..9i+8 never collide in-iteration ----
    {
        const int x = lane >> 3;
        const int y = lane & 7;
        #pragma unroll
        for (int i = 0; i < 4; ++i) {
            const float* bmi = bm + i * 9 * BMS;
            const float* umi = um + i * 3 * SSU;
            const float q01 = umi[x] + umi[SSU + y]
                            + bmi[0 * BMS + x * 9] + bmi[4 * BMS + y * 9]
                            + bmi[1 * BMS + x * 8 + y] + bmi[3 * BMS + y * 8 + x];
            const float q02 = umi[2 * SSU + y] + bmi[8 * BMS + y * 9]
                            + bmi[2 * BMS + x * 8 + y] + bmi[6 * BMS + y * 8 + x];
            const float q12 = bmi[5 * BMS + x * 8 + y] + bmi[7 * BMS + y * 8 + x];
            qq[(i * 3 + 0) * BMS + lane] = q01;
            qq[(i * 3 + 1) * BMS + lane] = q02;
            qq[(i * 3 + 2) * BMS + lane] = q12;
        }
    }

    // ---- phase 3: lane = ordered pair (a,bb), sweep cc for all 4 i ----
    float mn[4] = {INFINITY, INFINITY, INFINITY, INFINITY};
    if (lane < 56) {
        const int a  = lane / 7;
        const int o  = lane - a * 7;
        const int bb = o + (o >= a);
        #pragma unroll
        for (int i = 0; i < 4; ++i) {
            const float bs  = qq[(i * 3 + 0) * BMS + a * 8 + bb];
            const float4 c0 = *(const float4*)&qq[(i * 3 + 1) * BMS + a * 8];
            const float4 c1 = *(const float4*)&qq[(i * 3 + 1) * BMS + a * 8 + 4];
            const float4 d0 = *(const float4*)&qq[(i * 3 + 2) * BMS + bb * 8];
            const float4 d1 = *(const float4*)&qq[(i * 3 + 2) * BMS + bb * 8 + 4];
            float vv[8];
            vv[0] = c0.x + d0.x; vv[1] = c0.y + d0.y;
            vv[2] = c0.z + d0.z; vv[3] = c0.w + d0.w;
            vv[4] = c1.x + d1.x; vv[5] = c1.y + d1.y;
            vv[6] = c1.z + d1.z; vv[7] = c1.w + d1.w;
            float m = INFINITY;
            #pragma unroll
            for (int cc = 0; cc < 8; ++cc) {
                const float s = (cc == a || cc == bb) ? INFINITY : (bs + vv[cc]);
                m = fminf(m, s);
            }
            mn[i] = m;
        }
    }
    #pragma unroll
    for (int s = 1; s <= 32; s <<= 1) {
        #pragma unroll
        for (int i = 0; i < 4; ++i) mn[i] = fminf(mn[i], __shfl_xor(mn[i], s));
    }

    if (lane == 0) {
        const float mx = fmaxf(fmaxf(mn[0], mn[1]), fmaxf(mn[2], mn[3]));
        const float e0 = expf(mn[0] - mx), e1 = expf(mn[1] - mx);
        const float e2 = expf(mn[2] - mx), e3 = expf(mn[3] - mx);
        const float inv = 1.f / (e0 + e1 + e2 + e3);
        *(float4*)(out + (size_t)b * 4) =
            make_float4((e0 + e1) * inv, (e2 + e3) * inv, 0.f, 0.f);
    }
}

extern "C" void kernel_launch(void* const* d_in, const int* in_sizes, int n_in,
                              void* d_out, int out_size, void* d_ws, size_t ws_size,
                              hipStream_t stream) {
    const float* uf = (const float*)d_in[0];   // (4096,8,64)
    const float* bf = (const float*)d_in[1];   // (4096,8,8,64)
    const float* ru = (const float*)d_in[2];   // (4,3,64)
    const float* rb = (const float*)d_in[3];   // (4,3,3,64)
    float* out = (float*)d_out;                // (4096,4)

    const int B = in_sizes[0] / (8 * 64);      // 4096
    rule_learner_kernel<<<B, 64, 0, stream>>>(uf, bf, ru, rb, out);
}

// Round 16
// 21.992 us; speedup vs baseline: 1.3103x; 1.3103x over previous
//
#include <hip/hip_runtime.h>
#include <math.h>

// B=4096, O=8, E=64, I=4, V=3, P=perm(8,3)=336
// unary_feats  (B,8,64)   f32
// binary_feats (B,8,8,64) f32
// rule_unary   (4,3,64)   f32  = [12][64]
// rule_binary  (4,3,3,64) f32  = [36][64]  (rule = i*9 + n*3 + m)
// out          (B,4)      f32  (col0=sel0+sel1, col1=sel2+sel3, col2=col3=0)
//
// v16 = v11 (wave-autonomous, 2 elem/wave, zero barriers, single dispatch)
// with ALL feature loads (both elements, 40 dwordx4 / 36KB per wave) issued
// at KERNEL ENTRY: the full memory demand is in flight from t=0, elem1's
// data lands during elem0's compute, and the ~12us/CU memory stream fully
// overlaps the ~10us/CU compute chain (v11 exposed elem0's latency at each
// wave head and only prefetched elem1 after phase 1).
// VGPR ~210 < 256 -> still 2 waves/SIMD under __launch_bounds__(64,2).

typedef __attribute__((ext_vector_type(8))) __bf16 bf16x8;
typedef __attribute__((ext_vector_type(4))) float  f32x4;

#define BMS 68
#define QS3 68

__device__ inline bf16x8 cvt2(const float4 v0, const float4 v1) {
    bf16x8 r;
    r[0] = (__bf16)v0.x; r[1] = (__bf16)v0.y; r[2] = (__bf16)v0.z; r[3] = (__bf16)v0.w;
    r[4] = (__bf16)v1.x; r[5] = (__bf16)v1.y; r[6] = (__bf16)v1.z; r[7] = (__bf16)v1.w;
    return r;
}

__global__ __launch_bounds__(64, 2) void rule_learner_kernel(
    const float* __restrict__ uf,    // (B,8,64)
    const float* __restrict__ bfe,   // (B,8,8,64)
    const float* __restrict__ ru,    // [12][64]
    const float* __restrict__ rb,    // [36][64]
    float* __restrict__ out)         // (B,4)
{
    const int b0    = blockIdx.x * 2;
    const int lane  = threadIdx.x;   // one wave per block
    const int row16 = lane & 15;
    const int kg    = lane >> 4;
    const int kb    = kg * 8;

    __shared__ float bm[36 * BMS];   // 9792 B  [rule][pos]
    __shared__ float um[12 * 12];    // 576 B   [i*3+n][v]
    __shared__ float q [12 * QS3];   // 3264 B  [i*3+t][pair]

    // ---- ALL feature loads, BOTH elements, issued at kernel entry ----
    float4 af[2][4][4], uA[2][4];
    #pragma unroll
    for (int e = 0; e < 2; ++e) {
        const float* base = bfe + (size_t)(b0 + e) * 4096;
        #pragma unroll
        for (int t = 0; t < 4; ++t) {
            const float* rp = base + (size_t)(t * 16 + row16) * 64 + kb;
            af[e][t][0] = *(const float4*)rp;
            af[e][t][1] = *(const float4*)(rp + 4);
            af[e][t][2] = *(const float4*)(rp + 32);
            af[e][t][3] = *(const float4*)(rp + 36);
        }
        const float* up = uf + (size_t)(b0 + e) * 512
                        + (row16 < 8 ? row16 : 7) * 64 + kb;
        uA[e][0] = *(const float4*)up;
        uA[e][1] = *(const float4*)(up + 4);
        uA[e][2] = *(const float4*)(up + 32);
        uA[e][3] = *(const float4*)(up + 36);
    }

    // ---- rule fragments packed in-wave (L1-hot f32; clamp padding) ----
    bf16x8 rbf[6], ruf0, ruf1;
    {
        #pragma unroll
        for (int nt = 0; nt < 3; ++nt) {
            const int rule = nt * 16 + row16;
            const float* rp = rb + (rule < 36 ? rule : 35) * 64 + kb;
            rbf[nt * 2 + 0] = cvt2(*(const float4*)rp,        *(const float4*)(rp + 4));
            rbf[nt * 2 + 1] = cvt2(*(const float4*)(rp + 32), *(const float4*)(rp + 36));
        }
        const float* up = ru + (row16 < 12 ? row16 : 11) * 64 + kb;
        ruf0 = cvt2(*(const float4*)up,        *(const float4*)(up + 4));
        ruf1 = cvt2(*(const float4*)(up + 32), *(const float4*)(up + 36));
    }

    #pragma unroll
    for (int e = 0; e < 2; ++e) {
        // ---- phase 1: MFMA matches into bm/um ----
        #pragma unroll
        for (int t = 0; t < 4; ++t) {
            const bf16x8 a0 = cvt2(af[e][t][0], af[e][t][1]);
            const bf16x8 a1 = cvt2(af[e][t][2], af[e][t][3]);
            #pragma unroll
            for (int nt = 0; nt < 3; ++nt) {
                f32x4 acc = {0.f, 0.f, 0.f, 0.f};
                acc = __builtin_amdgcn_mfma_f32_16x16x32_bf16(a0, rbf[nt * 2 + 0], acc, 0, 0, 0);
                acc = __builtin_amdgcn_mfma_f32_16x16x32_bf16(a1, rbf[nt * 2 + 1], acc, 0, 0, 0);
                const int rule = nt * 16 + row16;
                if (rule < 36)
                    *(float4*)&bm[rule * BMS + t * 16 + kg * 4] = *(float4*)&acc;
            }
        }
        {
            const bf16x8 ua0 = cvt2(uA[e][0], uA[e][1]);
            const bf16x8 ua1 = cvt2(uA[e][2], uA[e][3]);
            f32x4 acc = {0.f, 0.f, 0.f, 0.f};
            acc = __builtin_amdgcn_mfma_f32_16x16x32_bf16(ua0, ruf0, acc, 0, 0, 0);
            acc = __builtin_amdgcn_mfma_f32_16x16x32_bf16(ua1, ruf1, acc, 0, 0, 0);
            if (row16 < 12 && kg < 2)
                *(float4*)&um[row16 * 12 + kg * 4] = *(float4*)&acc;
        }

        // ---- phase 2: q-tables for all 4 rule-sets (lane = pair (x,y)) ----
        {
            const int x = lane >> 3;
            const int y = lane & 7;
            #pragma unroll
            for (int i = 0; i < 4; ++i) {
                const float* bmi = bm + i * 9 * BMS;
                const float* umi = um + i * 3 * 12;
                const float q01 = umi[x] + umi[12 + y]
                                + bmi[0 * BMS + x * 9] + bmi[4 * BMS + y * 9]
                                + bmi[1 * BMS + x * 8 + y] + bmi[3 * BMS + y * 8 + x];
                const float q02 = umi[24 + y] + bmi[8 * BMS + y * 9]
                                + bmi[2 * BMS + x * 8 + y] + bmi[6 * BMS + y * 8 + x];
                const float q12 = bmi[5 * BMS + x * 8 + y] + bmi[7 * BMS + y * 8 + x];
                q[(i * 3 + 0) * QS3 + lane] = q01;
                q[(i * 3 + 1) * QS3 + lane] = q02;
                q[(i * 3 + 2) * QS3 + lane] = q12;
            }
        }

        // ---- phase 3: lane = ordered pair (a,bb), sweep cc for all 4 i ----
        float mn[4] = {INFINITY, INFINITY, INFINITY, INFINITY};
        if (lane < 56) {
            const int a  = lane / 7;
            const int o  = lane - a * 7;
            const int bb = o + (o >= a);
            #pragma unroll
            for (int i = 0; i < 4; ++i) {
                const float bs  = q[(i * 3 + 0) * QS3 + a * 8 + bb];
                const float4 c0 = *(const float4*)&q[(i * 3 + 1) * QS3 + a * 8];
                const float4 c1 = *(const float4*)&q[(i * 3 + 1) * QS3 + a * 8 + 4];
                const float4 d0 = *(const float4*)&q[(i * 3 + 2) * QS3 + bb * 8];
                const float4 d1 = *(const float4*)&q[(i * 3 + 2) * QS3 + bb * 8 + 4];
                float vv[8];
                vv[0] = c0.x + d0.x; vv[1] = c0.y + d0.y;
                vv[2] = c0.z + d0.z; vv[3] = c0.w + d0.w;
                vv[4] = c1.x + d1.x; vv[5] = c1.y + d1.y;
                vv[6] = c1.z + d1.z; vv[7] = c1.w + d1.w;
                float m = INFINITY;
                #pragma unroll
                for (int cc = 0; cc < 8; ++cc) {
                    const float s = (cc == a || cc == bb) ? INFINITY : (bs + vv[cc]);
                    m = fminf(m, s);
                }
                mn[i] = m;
            }
        }
        #pragma unroll
        for (int s = 1; s <= 32; s <<= 1) {
            #pragma unroll
            for (int i = 0; i < 4; ++i) mn[i] = fminf(mn[i], __shfl_xor(mn[i], s));
        }
        if (lane == 0) {
            const float mx = fmaxf(fmaxf(mn[0], mn[1]), fmaxf(mn[2], mn[3]));
            const float e0 = expf(mn[0] - mx), e1 = expf(mn[1] - mx);
            const float e2 = expf(mn[2] - mx), e3 = expf(mn[3] - mx);
            const float inv = 1.f / (e0 + e1 + e2 + e3);
            *(float4*)(out + (size_t)(b0 + e) * 4) =
                make_float4((e0 + e1) * inv, (e2 + e3) * inv, 0.f, 0.f);
        }

        // ---- LDS reuse guard between elements (WAR): DS-only wait; elem1's
        // loads are already long in flight. sched_barrier blocks hoisting. ----
        if (e == 0) {
            asm volatile("s_waitcnt lgkmcnt(0)" ::: "memory");
            __builtin_amdgcn_sched_barrier(0);
        }
    }
}

extern "C" void kernel_launch(void* const* d_in, const int* in_sizes, int n_in,
                              void* d_out, int out_size, void* d_ws, size_t ws_size,
                              hipStream_t stream) {
    const float* uf = (const float*)d_in[0];   // (4096,8,64)
    const float* bf = (const float*)d_in[1];   // (4096,8,8,64)
    const float* ru = (const float*)d_in[2];   // (4,3,64)
    const float* rb = (const float*)d_in[3];   // (4,3,3,64)
    float* out = (float*)d_out;                // (4096,4)

    const int B = in_sizes[0] / (8 * 64);      // 4096
    rule_learner_kernel<<<B / 2, 64, 0, stream>>>(uf, bf, ru, rb, out);
}

// Round 17
// 21.148 us; speedup vs baseline: 1.3626x; 1.0399x over previous
//
#include <hip/hip_runtime.h>
#include <math.h>

// B=4096, O=8, E=64, I=4, V=3, P=perm(8,3)=336
// unary_feats  (B,8,64)   f32
// binary_feats (B,8,8,64) f32
// rule_unary   (4,3,64)   f32  = [12][64]
// rule_binary  (4,3,3,64) f32  = [36][64]  (rule = i*9 + n*3 + m)
// out          (B,4)      f32  (col0=sel0+sel1, col1=sel2+sel3, col2=col3=0)
//
// v17 = v11's algorithm with 4 elements per wave (grid 1024) and a rolling
// 1-ahead prefetch: while element e computes (MFMA -> phase2 -> phase3),
// element e+1's 20 dwordx4 are in flight. Rule packing amortized 4x.
// Register discipline: only ONE element prefetched as float4 (80 VGPR);
// current element converted to bf16 fragments at use. Zero barriers;
// LDS reuse across elements guarded by lgkmcnt(0)+sched_barrier only
// (DS-only drain keeps the global prefetch in flight).

typedef __attribute__((ext_vector_type(8))) __bf16 bf16x8;
typedef __attribute__((ext_vector_type(4))) float  f32x4;

#define BMS 68
#define QS3 68
#define EPW 4    // elements per wave

__device__ inline bf16x8 cvt2(const float4 v0, const float4 v1) {
    bf16x8 r;
    r[0] = (__bf16)v0.x; r[1] = (__bf16)v0.y; r[2] = (__bf16)v0.z; r[3] = (__bf16)v0.w;
    r[4] = (__bf16)v1.x; r[5] = (__bf16)v1.y; r[6] = (__bf16)v1.z; r[7] = (__bf16)v1.w;
    return r;
}

__global__ __launch_bounds__(64, 2) void rule_learner_kernel(
    const float* __restrict__ uf,    // (B,8,64)
    const float* __restrict__ bfe,   // (B,8,8,64)
    const float* __restrict__ ru,    // [12][64]
    const float* __restrict__ rb,    // [36][64]
    float* __restrict__ out)         // (B,4)
{
    const int b0    = blockIdx.x * EPW;
    const int lane  = threadIdx.x;   // one wave per block
    const int row16 = lane & 15;
    const int kg    = lane >> 4;
    const int kb    = kg * 8;

    __shared__ float bm[36 * BMS];   // 9792 B  [rule][pos]
    __shared__ float um[12 * 12];    // 576 B   [i*3+n][v]
    __shared__ float q [12 * QS3];   // 3264 B  [i*3+t][pair]

    // ---- elem0 feature loads (the only exposed-latency load) ----
    float4 af[4][4], uA[4];
    {
        const float* base = bfe + (size_t)b0 * 4096;
        #pragma unroll
        for (int t = 0; t < 4; ++t) {
            const float* rp = base + (size_t)(t * 16 + row16) * 64 + kb;
            af[t][0] = *(const float4*)rp;
            af[t][1] = *(const float4*)(rp + 4);
            af[t][2] = *(const float4*)(rp + 32);
            af[t][3] = *(const float4*)(rp + 36);
        }
        const float* up = uf + (size_t)b0 * 512 + (row16 < 8 ? row16 : 7) * 64 + kb;
        uA[0] = *(const float4*)up;        uA[1] = *(const float4*)(up + 4);
        uA[2] = *(const float4*)(up + 32); uA[3] = *(const float4*)(up + 36);
    }

    // ---- rule fragments packed in-wave once (L1-hot f32; clamp padding) ----
    bf16x8 rbf[6], ruf0, ruf1;
    {
        #pragma unroll
        for (int nt = 0; nt < 3; ++nt) {
            const int rule = nt * 16 + row16;
            const float* rp = rb + (rule < 36 ? rule : 35) * 64 + kb;
            rbf[nt * 2 + 0] = cvt2(*(const float4*)rp,        *(const float4*)(rp + 4));
            rbf[nt * 2 + 1] = cvt2(*(const float4*)(rp + 32), *(const float4*)(rp + 36));
        }
        const float* up = ru + (row16 < 12 ? row16 : 11) * 64 + kb;
        ruf0 = cvt2(*(const float4*)up,        *(const float4*)(up + 4));
        ruf1 = cvt2(*(const float4*)(up + 32), *(const float4*)(up + 36));
    }

    #pragma unroll
    for (int e = 0; e < EPW; ++e) {
        // ---- phase 1: MFMA matches into bm/um (consumes af/uA) ----
        #pragma unroll
        for (int t = 0; t < 4; ++t) {
            const bf16x8 a0 = cvt2(af[t][0], af[t][1]);
            const bf16x8 a1 = cvt2(af[t][2], af[t][3]);
            #pragma unroll
            for (int nt = 0; nt < 3; ++nt) {
                f32x4 acc = {0.f, 0.f, 0.f, 0.f};
                acc = __builtin_amdgcn_mfma_f32_16x16x32_bf16(a0, rbf[nt * 2 + 0], acc, 0, 0, 0);
                acc = __builtin_amdgcn_mfma_f32_16x16x32_bf16(a1, rbf[nt * 2 + 1], acc, 0, 0, 0);
                const int rule = nt * 16 + row16;
                if (rule < 36)
                    *(float4*)&bm[rule * BMS + t * 16 + kg * 4] = *(float4*)&acc;
            }
        }
        {
            const bf16x8 ua0 = cvt2(uA[0], uA[1]);
            const bf16x8 ua1 = cvt2(uA[2], uA[3]);
            f32x4 acc = {0.f, 0.f, 0.f, 0.f};
            acc = __builtin_amdgcn_mfma_f32_16x16x32_bf16(ua0, ruf0, acc, 0, 0, 0);
            acc = __builtin_amdgcn_mfma_f32_16x16x32_bf16(ua1, ruf1, acc, 0, 0, 0);
            if (row16 < 12 && kg < 2)
                *(float4*)&um[row16 * 12 + kg * 4] = *(float4*)&acc;
        }

        // ---- issue elem e+1 loads NOW (af/uA regs are free again; latency
        //      hides under this element's phases 2-3) ----
        if (e + 1 < EPW) {
            const float* base = bfe + (size_t)(b0 + e + 1) * 4096;
            #pragma unroll
            for (int t = 0; t < 4; ++t) {
                const float* rp = base + (size_t)(t * 16 + row16) * 64 + kb;
                af[t][0] = *(const float4*)rp;
                af[t][1] = *(const float4*)(rp + 4);
                af[t][2] = *(const float4*)(rp + 32);
                af[t][3] = *(const float4*)(rp + 36);
            }
            const float* up = uf + (size_t)(b0 + e + 1) * 512
                            + (row16 < 8 ? row16 : 7) * 64 + kb;
            uA[0] = *(const float4*)up;        uA[1] = *(const float4*)(up + 4);
            uA[2] = *(const float4*)(up + 32); uA[3] = *(const float4*)(up + 36);
        }

        // ---- phase 2: q-tables for all 4 rule-sets (lane = pair (x,y)) ----
        {
            const int x = lane >> 3;
            const int y = lane & 7;
            #pragma unroll
            for (int i = 0; i < 4; ++i) {
                const float* bmi = bm + i * 9 * BMS;
                const float* umi = um + i * 3 * 12;
                const float q01 = umi[x] + umi[12 + y]
                                + bmi[0 * BMS + x * 9] + bmi[4 * BMS + y * 9]
                                + bmi[1 * BMS + x * 8 + y] + bmi[3 * BMS + y * 8 + x];
                const float q02 = umi[24 + y] + bmi[8 * BMS + y * 9]
                                + bmi[2 * BMS + x * 8 + y] + bmi[6 * BMS + y * 8 + x];
                const float q12 = bmi[5 * BMS + x * 8 + y] + bmi[7 * BMS + y * 8 + x];
                q[(i * 3 + 0) * QS3 + lane] = q01;
                q[(i * 3 + 1) * QS3 + lane] = q02;
                q[(i * 3 + 2) * QS3 + lane] = q12;
            }
        }

        // ---- phase 3: lane = ordered pair (a,bb), sweep cc for all 4 i ----
        float mn[4] = {INFINITY, INFINITY, INFINITY, INFINITY};
        if (lane < 56) {
            const int a  = lane / 7;
            const int o  = lane - a * 7;
            const int bb = o + (o >= a);
            #pragma unroll
            for (int i = 0; i < 4; ++i) {
                const float bs  = q[(i * 3 + 0) * QS3 + a * 8 + bb];
                const float4 c0 = *(const float4*)&q[(i * 3 + 1) * QS3 + a * 8];
                const float4 c1 = *(const float4*)&q[(i * 3 + 1) * QS3 + a * 8 + 4];
                const float4 d0 = *(const float4*)&q[(i * 3 + 2) * QS3 + bb * 8];
                const float4 d1 = *(const float4*)&q[(i * 3 + 2) * QS3 + bb * 8 + 4];
                float vv[8];
                vv[0] = c0.x + d0.x; vv[1] = c0.y + d0.y;
                vv[2] = c0.z + d0.z; vv[3] = c0.w + d0.w;
                vv[4] = c1.x + d1.x; vv[5] = c1.y + d1.y;
                vv[6] = c1.z + d1.z; vv[7] = c1.w + d1.w;
                float m = INFINITY;
                #pragma unroll
                for (int cc = 0; cc < 8; ++cc) {
                    const float s = (cc == a || cc == bb) ? INFINITY : (bs + vv[cc]);
                    m = fminf(m, s);
                }
                mn[i] = m;
            }
        }
        #pragma unroll
        for (int s = 1; s <= 32; s <<= 1) {
            #pragma unroll
            for (int i = 0; i < 4; ++i) mn[i] = fminf(mn[i], __shfl_xor(mn[i], s));
        }
        if (lane == 0) {
            const float mx = fmaxf(fmaxf(mn[0], mn[1]), fmaxf(mn[2], mn[3]));
            const float e0 = expf(mn[0] - mx), e1 = expf(mn[1] - mx);
            const float e2 = expf(mn[2] - mx), e3 = expf(mn[3] - mx);
            const float inv = 1.f / (e0 + e1 + e2 + e3);
            *(float4*)(out + (size_t)(b0 + e) * 4) =
                make_float4((e0 + e1) * inv, (e2 + e3) * inv, 0.f, 0.f);
        }

        // ---- LDS reuse guard (WAR) between elements: DS-only drain keeps
        //      the next element's global prefetch in flight (rule #18). ----
        if (e + 1 < EPW) {
            asm volatile("s_waitcnt lgkmcnt(0)" ::: "memory");
            __builtin_amdgcn_sched_barrier(0);
        }
    }
}

extern "C" void kernel_launch(void* const* d_in, const int* in_sizes, int n_in,
                              void* d_out, int out_size, void* d_ws, size_t ws_size,
                              hipStream_t stream) {
    const float* uf = (const float*)d_in[0];   // (4096,8,64)
    const float* bf = (const float*)d_in[1];   // (4096,8,8,64)
    const float* ru = (const float*)d_in[2];   // (4,3,64)
    const float* rb = (const float*)d_in[3];   // (4,3,3,64)
    float* out = (float*)d_out;                // (4096,4)

    const int B = in_sizes[0] / (8 * 64);      // 4096
    rule_learner_kernel<<<B / EPW, 64, 0, stream>>>(uf, bf, ru, rb, out);
}